// Round 1
// baseline (845.900 us; speedup 1.0000x reference)
//
#include <hip/hip_runtime.h>
#include <math.h>

#define N_NODES   100000
#define N_EDGES   1600000
#define N_FEAT    128
#define H_DIM     32
#define N_CLASSES 10
#define N_GRAPHS  64

// ---------------- utility ----------------
__global__ void zero_kernel(float* p, int n) {
    int i = blockIdx.x * blockDim.x + threadIdx.x;
    if (i < n) p[i] = 0.f;
}

// deg[dst] += 1 per edge
__global__ void degree_kernel(const int* __restrict__ dst, float* __restrict__ deg, int E) {
    int e = blockIdx.x * blockDim.x + threadIdx.x;
    if (e < E) atomicAdd(&deg[dst[e]], 1.0f);
}

// dis[i] = (deg[i] + 1)^-1/2   (self loop included)
__global__ void dis_kernel(float* __restrict__ deg, int n) {
    int i = blockIdx.x * blockDim.x + threadIdx.x;
    if (i < n) deg[i] = rsqrtf(deg[i] + 1.0f);
}

// ---------------- h = x @ W1 : (N x 128) @ (128 x 32) ----------------
// 8 rows per 256-thread block; W1 (16KB) + x tile (4KB) in LDS.
__global__ void gemm128_kernel(const float* __restrict__ x, const float* __restrict__ W,
                               float* __restrict__ out) {
    __shared__ float ws[128 * 32];
    __shared__ float xs[8][128];
    int tid = threadIdx.x;
    for (int i = tid; i < 128 * 32; i += 256) ws[i] = W[i];
    int row0 = blockIdx.x * 8;
    for (int i = tid; i < 8 * 128; i += 256)
        xs[i >> 7][i & 127] = x[(row0 + (i >> 7)) * N_FEAT + (i & 127)];
    __syncthreads();
    int r = tid >> 5, j = tid & 31;
    float acc = 0.f;
#pragma unroll
    for (int k = 0; k < 128; k++) acc += xs[r][k] * ws[k * 32 + j];
    out[(row0 + r) * H_DIM + j] = acc;
}

// ---------------- out = (relu?) in @ W : (N x 32) @ (32 x 32) ----------------
// 32 rows per 256-thread block; each thread computes 4 rows x 1 col.
template <bool RELU>
__global__ void gemm32_kernel(const float* __restrict__ in, const float* __restrict__ W,
                              float* __restrict__ out) {
    __shared__ float ws[32 * 32];
    __shared__ float xs[32][32];
    int tid = threadIdx.x;
    for (int i = tid; i < 1024; i += 256) ws[i] = W[i];
    int row0 = blockIdx.x * 32;
    for (int i = tid; i < 1024; i += 256) {
        float v = in[row0 * 32 + i];
        if (RELU) v = fmaxf(v, 0.f);
        xs[i >> 5][i & 31] = v;
    }
    __syncthreads();
    int j = tid & 31;
    int r0 = tid >> 5;  // 0..7
    float acc[4] = {0.f, 0.f, 0.f, 0.f};
#pragma unroll
    for (int k = 0; k < 32; k++) {
        float w = ws[k * 32 + j];
#pragma unroll
        for (int m = 0; m < 4; m++) acc[m] += xs[r0 + 8 * m][k] * w;
    }
#pragma unroll
    for (int m = 0; m < 4; m++) out[(row0 + r0 + 8 * m) * 32 + j] = acc[m];
}

// out[i,j] = dis[i]^2 * h[i,j] + b[j]   (self-loop term + bias, before scatter)
__global__ void prefill_kernel(const float* __restrict__ h, const float* __restrict__ dis,
                               const float* __restrict__ b, float* __restrict__ out, int n) {
    int t = blockIdx.x * blockDim.x + threadIdx.x;
    if (t < n) {
        int i = t >> 5, j = t & 31;
        float d = dis[i];
        out[t] = d * d * h[t] + b[j];
    }
}

// out[dst,j] += h[src,j] * dis[src]*dis[dst]  (one thread per (edge, feature))
__global__ void scatter_kernel(const int* __restrict__ src, const int* __restrict__ dst,
                               const float* __restrict__ dis, const float* __restrict__ h,
                               float* __restrict__ out, int E) {
    int t = blockIdx.x * blockDim.x + threadIdx.x;
    int e = t >> 5, j = t & 31;
    if (e < E) {
        int s = src[e], d = dst[e];
        float norm = dis[s] * dis[d];
        atomicAdd(&out[d * 32 + j], h[s * 32 + j] * norm);
    }
}

// ---------------- fused mean-pool + linear + softmax ----------------
// one block per graph; batch_mapping is sorted so segment = [lower_bound(g), lower_bound(g+1))
__global__ void pool_head_kernel(const float* __restrict__ h, const int* __restrict__ batch,
                                 const float* __restrict__ Wl, const float* __restrict__ bl,
                                 float* __restrict__ out) {
    __shared__ int seg[2];
    __shared__ float red[8][32];
    __shared__ float pooled[32];
    __shared__ float logits[N_CLASSES];
    int g = blockIdx.x, tid = threadIdx.x;
    if (tid == 0) {
        int lo = 0, hi = N_NODES;
        while (lo < hi) { int m = (lo + hi) >> 1; if (batch[m] < g) lo = m + 1; else hi = m; }
        seg[0] = lo;
        lo = seg[0]; hi = N_NODES;
        while (lo < hi) { int m = (lo + hi) >> 1; if (batch[m] < g + 1) lo = m + 1; else hi = m; }
        seg[1] = lo;
    }
    __syncthreads();
    int lo = seg[0], hi = seg[1];
    int j = tid & 31, rs = tid >> 5;
    float acc = 0.f;
    for (int i = lo + rs; i < hi; i += 8) acc += h[i * 32 + j];
    red[rs][j] = acc;
    __syncthreads();
    if (tid < 32) {
        float s = 0.f;
#pragma unroll
        for (int r = 0; r < 8; r++) s += red[r][j];
        float cnt = (float)(hi - lo);
        pooled[j] = s / fmaxf(cnt, 1.0f);
    }
    __syncthreads();
    if (tid < N_CLASSES) {
        float l = bl[tid];
#pragma unroll
        for (int k = 0; k < 32; k++) l += pooled[k] * Wl[k * N_CLASSES + tid];
        logits[tid] = l;
    }
    __syncthreads();
    if (tid < N_CLASSES) {
        float m = -1e30f;
#pragma unroll
        for (int c = 0; c < N_CLASSES; c++) m = fmaxf(m, logits[c]);
        float s = 0.f;
#pragma unroll
        for (int c = 0; c < N_CLASSES; c++) s += expf(logits[c] - m);
        out[g * N_CLASSES + tid] = expf(logits[tid] - m) / s;
    }
}

extern "C" void kernel_launch(void* const* d_in, const int* in_sizes, int n_in,
                              void* d_out, int out_size, void* d_ws, size_t ws_size,
                              hipStream_t stream) {
    const float* x     = (const float*)d_in[0];
    const int*   ei    = (const int*)d_in[1];
    const int*   batch = (const int*)d_in[2];
    const float* W1 = (const float*)d_in[3];
    const float* b1 = (const float*)d_in[4];
    const float* W2 = (const float*)d_in[5];
    const float* b2 = (const float*)d_in[6];
    const float* W3 = (const float*)d_in[7];
    const float* b3 = (const float*)d_in[8];
    const float* Wl = (const float*)d_in[9];
    const float* bl = (const float*)d_in[10];
    float* out = (float*)d_out;

    const int* src = ei;            // edge_index[0]
    const int* dst = ei + N_EDGES;  // edge_index[1]

    // workspace layout (floats)
    float* ws    = (float*)d_ws;
    float* dis   = ws;                          // N_NODES (deg, then dis in-place)
    float* h_tmp = ws + 100352;                 // N_NODES * 32
    float* h_agg = h_tmp + N_NODES * H_DIM;     // N_NODES * 32

    const int NB_N   = (N_NODES + 255) / 256;
    const int NB_E   = (N_EDGES + 255) / 256;
    const int NB_N32 = (N_NODES * H_DIM) / 256;  // 12500
    const int NB_E32 = (N_EDGES * H_DIM) / 256;  // 200000

    // degree + normalization
    zero_kernel<<<NB_N, 256, 0, stream>>>(dis, N_NODES);
    degree_kernel<<<NB_E, 256, 0, stream>>>(dst, dis, N_EDGES);
    dis_kernel<<<NB_N, 256, 0, stream>>>(dis, N_NODES);

    // layer 1
    gemm128_kernel<<<N_NODES / 8, 256, 0, stream>>>(x, W1, h_tmp);
    prefill_kernel<<<NB_N32, 256, 0, stream>>>(h_tmp, dis, b1, h_agg, N_NODES * H_DIM);
    scatter_kernel<<<NB_E32, 256, 0, stream>>>(src, dst, dis, h_tmp, h_agg, N_EDGES);

    // layer 2 (relu on read of h_agg)
    gemm32_kernel<true><<<N_NODES / 32, 256, 0, stream>>>(h_agg, W2, h_tmp);
    prefill_kernel<<<NB_N32, 256, 0, stream>>>(h_tmp, dis, b2, h_agg, N_NODES * H_DIM);
    scatter_kernel<<<NB_E32, 256, 0, stream>>>(src, dst, dis, h_tmp, h_agg, N_EDGES);

    // layer 3
    gemm32_kernel<true><<<N_NODES / 32, 256, 0, stream>>>(h_agg, W3, h_tmp);
    prefill_kernel<<<NB_N32, 256, 0, stream>>>(h_tmp, dis, b3, h_agg, N_NODES * H_DIM);
    scatter_kernel<<<NB_E32, 256, 0, stream>>>(src, dst, dis, h_tmp, h_agg, N_EDGES);

    // pool + classifier + softmax
    pool_head_kernel<<<N_GRAPHS, 256, 0, stream>>>(h_agg, batch, Wl, bl, out);
}

// Round 2
// 579.257 us; speedup vs baseline: 1.4603x; 1.4603x over previous
//
#include <hip/hip_runtime.h>
#include <math.h>

#define N_NODES   100000
#define N_EDGES   1600000
#define N_FEAT    128
#define H_DIM     32
#define N_CLASSES 10
#define N_GRAPHS  64
#define NBLK      ((N_NODES + 255) / 256)   // 391

// ---------------- CSR build ----------------
__global__ void zero_counts_kernel(int* __restrict__ counts) {
    int i = blockIdx.x * blockDim.x + threadIdx.x;
    if (i < N_NODES) counts[i] = 0;
}

__global__ void hist_kernel(const int* __restrict__ dst, int* __restrict__ counts) {
    int e = blockIdx.x * blockDim.x + threadIdx.x;
    if (e < N_EDGES) atomicAdd(&counts[dst[e]], 1);
}

// per-block sums of counts
__global__ void scan_part1_kernel(const int* __restrict__ counts, int* __restrict__ bsums) {
    __shared__ int red[256];
    int t = threadIdx.x;
    int i = blockIdx.x * 256 + t;
    red[t] = (i < N_NODES) ? counts[i] : 0;
    __syncthreads();
    for (int off = 128; off > 0; off >>= 1) {
        if (t < off) red[t] += red[t + off];
        __syncthreads();
    }
    if (t == 0) bsums[blockIdx.x] = red[0];
}

// exclusive scan of bsums (NBLK <= 512), in place
__global__ void scan_part2_kernel(int* __restrict__ bsums) {
    __shared__ int s[512];
    int t = threadIdx.x;
    int v = (t < NBLK) ? bsums[t] : 0;
    s[t] = v;
    __syncthreads();
    for (int off = 1; off < 512; off <<= 1) {
        int x = (t >= off) ? s[t - off] : 0;
        __syncthreads();
        s[t] += x;
        __syncthreads();
    }
    if (t < NBLK) bsums[t] = s[t] - v;  // exclusive
}

// row_ptr = blockOff + excl-scan-in-block; cursor copy; dis = rsqrt(count+1)
__global__ void scan_part3_kernel(const int* __restrict__ counts, const int* __restrict__ bsums,
                                  int* __restrict__ row_ptr, int* __restrict__ cursor,
                                  float* __restrict__ dis) {
    __shared__ int s[256];
    int t = threadIdx.x;
    int i = blockIdx.x * 256 + t;
    int v = (i < N_NODES) ? counts[i] : 0;
    s[t] = v;
    __syncthreads();
    for (int off = 1; off < 256; off <<= 1) {
        int x = (t >= off) ? s[t - off] : 0;
        __syncthreads();
        s[t] += x;
        __syncthreads();
    }
    if (i < N_NODES) {
        int rp = bsums[blockIdx.x] + s[t] - v;
        row_ptr[i] = rp;
        cursor[i] = rp;
        dis[i] = rsqrtf((float)v + 1.0f);
        if (i == N_NODES - 1) row_ptr[N_NODES] = N_EDGES;
    }
}

__global__ void fill_kernel(const int* __restrict__ src, const int* __restrict__ dst,
                            int* __restrict__ cursor, int* __restrict__ csr) {
    int e = blockIdx.x * blockDim.x + threadIdx.x;
    if (e < N_EDGES) {
        int pos = atomicAdd(&cursor[dst[e]], 1);
        csr[pos] = src[e];
    }
}

// ---------------- g = (x @ W1) * dis : (N x 128) @ (128 x 32) ----------------
__global__ void gemm128_kernel(const float* __restrict__ x, const float* __restrict__ W,
                               const float* __restrict__ dis, float* __restrict__ out) {
    __shared__ float ws[128 * 32];
    __shared__ float xs[8][128];
    int tid = threadIdx.x;
    for (int i = tid; i < 128 * 32; i += 256) ws[i] = W[i];
    int row0 = blockIdx.x * 8;
    for (int i = tid; i < 8 * 128; i += 256)
        xs[i >> 7][i & 127] = x[(row0 + (i >> 7)) * N_FEAT + (i & 127)];
    __syncthreads();
    int r = tid >> 5, j = tid & 31;
    float acc = 0.f;
#pragma unroll
    for (int k = 0; k < 128; k++) acc += xs[r][k] * ws[k * 32 + j];
    out[(row0 + r) * H_DIM + j] = acc * dis[row0 + r];
}

// ---------------- g = (relu(in) @ W) * dis : (N x 32) @ (32 x 32) ----------------
template <bool RELU>
__global__ void gemm32_kernel(const float* __restrict__ in, const float* __restrict__ W,
                              const float* __restrict__ dis, float* __restrict__ out) {
    __shared__ float ws[32 * 32];
    __shared__ float xs[32][32];
    int tid = threadIdx.x;
    for (int i = tid; i < 1024; i += 256) ws[i] = W[i];
    int row0 = blockIdx.x * 32;
    for (int i = tid; i < 1024; i += 256) {
        float v = in[row0 * 32 + i];
        if (RELU) v = fmaxf(v, 0.f);
        xs[i >> 5][i & 31] = v;
    }
    __syncthreads();
    int j = tid & 31;
    int r0 = tid >> 3 >> 2;            // 0..7
    r0 = tid >> 5;
    float acc[4] = {0.f, 0.f, 0.f, 0.f};
#pragma unroll
    for (int k = 0; k < 32; k++) {
        float w = ws[k * 32 + j];
#pragma unroll
        for (int m = 0; m < 4; m++) acc[m] += xs[r0 + 8 * m][k] * w;
    }
#pragma unroll
    for (int m = 0; m < 4; m++) {
        int row = row0 + r0 + 8 * m;
        out[row * 32 + j] = acc[m] * dis[row];
    }
}

// ---------------- gather: out[d] = dis[d]*(g[d] + sum g[src]) + b ----------------
__global__ void gather_kernel(const int* __restrict__ rp, const int* __restrict__ csr,
                              const float* __restrict__ g, const float* __restrict__ dis,
                              const float* __restrict__ b, float* __restrict__ out) {
    int tid = threadIdx.x;
    int row = blockIdx.x * 8 + (tid >> 5);
    int j = tid & 31;
    int lo = rp[row], hi = rp[row + 1];
    float acc0 = g[row * 32 + j];  // self loop: dis*g[d] = dis^2*h[d]
    float acc1 = 0.f;
    for (int base = lo; base < hi; base += 32) {
        int cnt = hi - base; if (cnt > 32) cnt = 32;
        int sid = (base + j < hi) ? csr[base + j] : 0;
        int k = 0;
        for (; k + 1 < cnt; k += 2) {
            int s0 = __shfl(sid, k, 32);
            int s1 = __shfl(sid, k + 1, 32);
            acc0 += g[s0 * 32 + j];
            acc1 += g[s1 * 32 + j];
        }
        if (k < cnt) {
            int s0 = __shfl(sid, k, 32);
            acc0 += g[s0 * 32 + j];
        }
    }
    out[row * 32 + j] = dis[row] * (acc0 + acc1) + b[j];
}

// ---------------- fused mean-pool + linear + softmax ----------------
__global__ void pool_head_kernel(const float* __restrict__ h, const int* __restrict__ batch,
                                 const float* __restrict__ Wl, const float* __restrict__ bl,
                                 float* __restrict__ out) {
    __shared__ int seg[2];
    __shared__ float red[8][32];
    __shared__ float pooled[32];
    __shared__ float logits[N_CLASSES];
    int g = blockIdx.x, tid = threadIdx.x;
    if (tid == 0) {
        int lo = 0, hi = N_NODES;
        while (lo < hi) { int m = (lo + hi) >> 1; if (batch[m] < g) lo = m + 1; else hi = m; }
        seg[0] = lo;
        lo = seg[0]; hi = N_NODES;
        while (lo < hi) { int m = (lo + hi) >> 1; if (batch[m] < g + 1) lo = m + 1; else hi = m; }
        seg[1] = lo;
    }
    __syncthreads();
    int lo = seg[0], hi = seg[1];
    int j = tid & 31, rs = tid >> 5;
    float acc = 0.f;
    for (int i = lo + rs; i < hi; i += 8) acc += h[i * 32 + j];
    red[rs][j] = acc;
    __syncthreads();
    if (tid < 32) {
        float s = 0.f;
#pragma unroll
        for (int r = 0; r < 8; r++) s += red[r][j];
        float cnt = (float)(hi - lo);
        pooled[j] = s / fmaxf(cnt, 1.0f);
    }
    __syncthreads();
    if (tid < N_CLASSES) {
        float l = bl[tid];
#pragma unroll
        for (int k = 0; k < 32; k++) l += pooled[k] * Wl[k * N_CLASSES + tid];
        logits[tid] = l;
    }
    __syncthreads();
    if (tid < N_CLASSES) {
        float m = -1e30f;
#pragma unroll
        for (int c = 0; c < N_CLASSES; c++) m = fmaxf(m, logits[c]);
        float s = 0.f;
#pragma unroll
        for (int c = 0; c < N_CLASSES; c++) s += expf(logits[c] - m);
        out[g * N_CLASSES + tid] = expf(logits[tid] - m) / s;
    }
}

extern "C" void kernel_launch(void* const* d_in, const int* in_sizes, int n_in,
                              void* d_out, int out_size, void* d_ws, size_t ws_size,
                              hipStream_t stream) {
    const float* x     = (const float*)d_in[0];
    const int*   ei    = (const int*)d_in[1];
    const int*   batch = (const int*)d_in[2];
    const float* W1 = (const float*)d_in[3];
    const float* b1 = (const float*)d_in[4];
    const float* W2 = (const float*)d_in[5];
    const float* b2 = (const float*)d_in[6];
    const float* W3 = (const float*)d_in[7];
    const float* b3 = (const float*)d_in[8];
    const float* Wl = (const float*)d_in[9];
    const float* bl = (const float*)d_in[10];
    float* out = (float*)d_out;

    const int* src = ei;            // edge_index[0]
    const int* dst = ei + N_EDGES;  // edge_index[1]

    // workspace layout
    int*   wsi     = (int*)d_ws;
    int*   counts  = wsi;                        // N_NODES
    int*   row_ptr = counts + N_NODES;           // N_NODES + 1
    int*   cursor  = row_ptr + N_NODES + 1;      // N_NODES
    int*   bsums   = cursor + N_NODES;           // 512
    int*   csr     = bsums + 512;                // N_EDGES
    float* dis     = (float*)(csr + N_EDGES);    // N_NODES
    float* g       = dis + N_NODES;              // N_NODES * 32
    float* h_agg   = g + N_NODES * H_DIM;        // N_NODES * 32

    const int NB_E = (N_EDGES + 255) / 256;  // 6250

    // ---- CSR build (also yields degree -> dis) ----
    zero_counts_kernel<<<NBLK, 256, 0, stream>>>(counts);
    hist_kernel<<<NB_E, 256, 0, stream>>>(dst, counts);
    scan_part1_kernel<<<NBLK, 256, 0, stream>>>(counts, bsums);
    scan_part2_kernel<<<1, 512, 0, stream>>>(bsums);
    scan_part3_kernel<<<NBLK, 256, 0, stream>>>(counts, bsums, row_ptr, cursor, dis);
    fill_kernel<<<NB_E, 256, 0, stream>>>(src, dst, cursor, csr);

    // ---- layer 1 ----
    gemm128_kernel<<<N_NODES / 8, 256, 0, stream>>>(x, W1, dis, g);
    gather_kernel<<<N_NODES / 8, 256, 0, stream>>>(row_ptr, csr, g, dis, b1, h_agg);

    // ---- layer 2 ----
    gemm32_kernel<true><<<N_NODES / 32, 256, 0, stream>>>(h_agg, W2, dis, g);
    gather_kernel<<<N_NODES / 8, 256, 0, stream>>>(row_ptr, csr, g, dis, b2, h_agg);

    // ---- layer 3 ----
    gemm32_kernel<true><<<N_NODES / 32, 256, 0, stream>>>(h_agg, W3, dis, g);
    gather_kernel<<<N_NODES / 8, 256, 0, stream>>>(row_ptr, csr, g, dis, b3, h_agg);

    // ---- pool + classifier + softmax ----
    pool_head_kernel<<<N_GRAPHS, 256, 0, stream>>>(h_agg, batch, Wl, bl, out);
}

// Round 7
// 514.489 us; speedup vs baseline: 1.6442x; 1.1259x over previous
//
#include <hip/hip_runtime.h>
#include <math.h>

#define N_NODES   100000
#define N_EDGES   1600000
#define N_FEAT    128
#define H_DIM     32
#define N_CLASSES 10
#define N_GRAPHS  64
#define NBLK      ((N_NODES + 255) / 256)   // 391

#define NS        8                          // dst slices (XCD-affine)
#define GPS       128                        // edge chunks per slice
#define NODES_PER_SLICE (N_NODES / NS)       // 12500
#define EDGES_PER_CHUNK (N_EDGES / GPS)      // 12500

// ---------------- CSR build ----------------
__global__ void zero_counts_kernel(int* __restrict__ counts) {
    int i = blockIdx.x * blockDim.x + threadIdx.x;
    if (i < N_NODES) counts[i] = 0;
}

// sliced histogram: block (slice=blockIdx&7, chunk=blockIdx>>3) scans its edge
// chunk, counts only dst in its slice -> atomics land in one XCD-local 50KB region
__global__ void hist_sliced_kernel(const int* __restrict__ dst, int* __restrict__ counts) {
    int slice = blockIdx.x & (NS - 1);
    int chunk = blockIdx.x >> 3;
    int lo_node = slice * NODES_PER_SLICE;
    int hi_node = lo_node + NODES_PER_SLICE;
    int e0 = chunk * EDGES_PER_CHUNK;
    int e1 = e0 + EDGES_PER_CHUNK;
    for (int e = e0 + threadIdx.x; e < e1; e += 256) {
        int d = dst[e];
        if (d >= lo_node && d < hi_node) atomicAdd(&counts[d], 1);
    }
}

// per-block sums of counts
__global__ void scan_part1_kernel(const int* __restrict__ counts, int* __restrict__ bsums) {
    __shared__ int red[256];
    int t = threadIdx.x;
    int i = blockIdx.x * 256 + t;
    red[t] = (i < N_NODES) ? counts[i] : 0;
    __syncthreads();
    for (int off = 128; off > 0; off >>= 1) {
        if (t < off) red[t] += red[t + off];
        __syncthreads();
    }
    if (t == 0) bsums[blockIdx.x] = red[0];
}

// exclusive scan of bsums (NBLK <= 512), in place
__global__ void scan_part2_kernel(int* __restrict__ bsums) {
    __shared__ int s[512];
    int t = threadIdx.x;
    int v = (t < NBLK) ? bsums[t] : 0;
    s[t] = v;
    __syncthreads();
    for (int off = 1; off < 512; off <<= 1) {
        int x = (t >= off) ? s[t - off] : 0;
        __syncthreads();
        s[t] += x;
        __syncthreads();
    }
    if (t < NBLK) bsums[t] = s[t] - v;  // exclusive
}

// row_ptr = blockOff + excl-scan-in-block; cursor copy; dis = rsqrt(count+1)
__global__ void scan_part3_kernel(const int* __restrict__ counts, const int* __restrict__ bsums,
                                  int* __restrict__ row_ptr, int* __restrict__ cursor,
                                  float* __restrict__ dis) {
    __shared__ int s[256];
    int t = threadIdx.x;
    int i = blockIdx.x * 256 + t;
    int v = (i < N_NODES) ? counts[i] : 0;
    s[t] = v;
    __syncthreads();
    for (int off = 1; off < 256; off <<= 1) {
        int x = (t >= off) ? s[t - off] : 0;
        __syncthreads();
        s[t] += x;
        __syncthreads();
    }
    if (i < N_NODES) {
        int rp = bsums[blockIdx.x] + s[t] - v;
        row_ptr[i] = rp;
        cursor[i] = rp;
        dis[i] = rsqrtf((float)v + 1.0f);
        if (i == N_NODES - 1) row_ptr[N_NODES] = N_EDGES;
    }
}

// sliced fill: writes for slice s land in a contiguous ~800KB csr region,
// resident in that XCD's L2 until lines fill -> kills write amplification
__global__ void fill_sliced_kernel(const int* __restrict__ src, const int* __restrict__ dst,
                                   int* __restrict__ cursor, int* __restrict__ csr) {
    int slice = blockIdx.x & (NS - 1);
    int chunk = blockIdx.x >> 3;
    int lo_node = slice * NODES_PER_SLICE;
    int hi_node = lo_node + NODES_PER_SLICE;
    int e0 = chunk * EDGES_PER_CHUNK;
    int e1 = e0 + EDGES_PER_CHUNK;
    for (int e = e0 + threadIdx.x; e < e1; e += 256) {
        int d = dst[e];
        if (d >= lo_node && d < hi_node) {
            int pos = atomicAdd(&cursor[d], 1);
            csr[pos] = src[e];
        }
    }
}

// ---------------- g = (x @ W1) * dis : (N x 128) @ (128 x 32) ----------------
__global__ void gemm128_kernel(const float* __restrict__ x, const float* __restrict__ W,
                               const float* __restrict__ dis, float* __restrict__ out) {
    __shared__ float ws[128 * 32];
    __shared__ float xs[8][128];
    int tid = threadIdx.x;
    const float4* W4 = (const float4*)W;
    float4* ws4 = (float4*)ws;
    for (int i = tid; i < 1024; i += 256) ws4[i] = W4[i];
    int row0 = blockIdx.x * 8;
    const float4* x4 = (const float4*)(x + (size_t)row0 * N_FEAT);
    float4* xs4 = (float4*)xs;
    xs4[tid] = x4[tid];  // 256 float4 = 8 rows x 128
    __syncthreads();
    int r = tid >> 5, j = tid & 31;
    float acc = 0.f;
#pragma unroll
    for (int k = 0; k < 128; k++) acc += xs[r][k] * ws[k * 32 + j];
    out[(row0 + r) * H_DIM + j] = acc * dis[row0 + r];
}

// ---------------- g = (relu(in) @ W) * dis : (N x 32) @ (32 x 32) ----------------
template <bool RELU>
__global__ void gemm32_kernel(const float* __restrict__ in, const float* __restrict__ W,
                              const float* __restrict__ dis, float* __restrict__ out) {
    __shared__ float ws[32 * 32];
    __shared__ float xs[32][32];
    int tid = threadIdx.x;
    const float4* W4 = (const float4*)W;
    float4* ws4 = (float4*)ws;
    for (int i = tid; i < 256; i += 256) ws4[i] = W4[i];
    int row0 = blockIdx.x * 32;
    const float4* in4 = (const float4*)(in + (size_t)row0 * 32);
    float4 v = in4[tid];
    if (RELU) {
        v.x = fmaxf(v.x, 0.f); v.y = fmaxf(v.y, 0.f);
        v.z = fmaxf(v.z, 0.f); v.w = fmaxf(v.w, 0.f);
    }
    ((float4*)xs)[tid] = v;
    __syncthreads();
    int j = tid & 31;
    int r0 = tid >> 5;  // 0..7
    float acc[4] = {0.f, 0.f, 0.f, 0.f};
#pragma unroll
    for (int k = 0; k < 32; k++) {
        float w = ws[k * 32 + j];
#pragma unroll
        for (int m = 0; m < 4; m++) acc[m] += xs[r0 + 8 * m][k] * w;
    }
#pragma unroll
    for (int m = 0; m < 4; m++) {
        int row = row0 + r0 + 8 * m;
        out[row * 32 + j] = acc[m] * dis[row];
    }
}

// ---------------- gather: out[d] = dis[d]*(g[d] + sum g[src]) + b ----------------
__global__ void gather_kernel(const int* __restrict__ rp, const int* __restrict__ csr,
                              const float* __restrict__ g, const float* __restrict__ dis,
                              const float* __restrict__ b, float* __restrict__ out) {
    int tid = threadIdx.x;
    int row = blockIdx.x * 8 + (tid >> 5);
    int j = tid & 31;
    int lo = rp[row], hi = rp[row + 1];
    float a0 = g[row * 32 + j];  // self loop: dis*g[d] = dis^2*h[d]
    float a1 = 0.f, a2 = 0.f, a3 = 0.f;
    for (int base = lo; base < hi; base += 32) {
        int cnt = hi - base; if (cnt > 32) cnt = 32;
        int sid = (base + j < hi) ? csr[base + j] : 0;
        int k = 0;
        for (; k + 3 < cnt; k += 4) {
            int s0 = __shfl(sid, k, 32);
            int s1 = __shfl(sid, k + 1, 32);
            int s2 = __shfl(sid, k + 2, 32);
            int s3 = __shfl(sid, k + 3, 32);
            a0 += g[s0 * 32 + j];
            a1 += g[s1 * 32 + j];
            a2 += g[s2 * 32 + j];
            a3 += g[s3 * 32 + j];
        }
        for (; k < cnt; k++) {
            a0 += g[__shfl(sid, k, 32) * 32 + j];
        }
    }
    out[row * 32 + j] = dis[row] * (a0 + a1 + a2 + a3) + b[j];
}

// ---------------- fused mean-pool + linear + softmax ----------------
__global__ void pool_head_kernel(const float* __restrict__ h, const int* __restrict__ batch,
                                 const float* __restrict__ Wl, const float* __restrict__ bl,
                                 float* __restrict__ out) {
    __shared__ int seg[2];
    __shared__ float red[8][32];
    __shared__ float pooled[32];
    __shared__ float logits[N_CLASSES];
    int g = blockIdx.x, tid = threadIdx.x;
    if (tid == 0) {
        int lo = 0, hi = N_NODES;
        while (lo < hi) { int m = (lo + hi) >> 1; if (batch[m] < g) lo = m + 1; else hi = m; }
        seg[0] = lo;
        lo = seg[0]; hi = N_NODES;
        while (lo < hi) { int m = (lo + hi) >> 1; if (batch[m] < g + 1) lo = m + 1; else hi = m; }
        seg[1] = lo;
    }
    __syncthreads();
    int lo = seg[0], hi = seg[1];
    int j = tid & 31, rs = tid >> 5;
    float acc = 0.f;
    for (int i = lo + rs; i < hi; i += 8) acc += h[i * 32 + j];
    red[rs][j] = acc;
    __syncthreads();
    if (tid < 32) {
        float s = 0.f;
#pragma unroll
        for (int r = 0; r < 8; r++) s += red[r][j];
        float cnt = (float)(hi - lo);
        pooled[j] = s / fmaxf(cnt, 1.0f);
    }
    __syncthreads();
    if (tid < N_CLASSES) {
        float l = bl[tid];
#pragma unroll
        for (int k = 0; k < 32; k++) l += pooled[k] * Wl[k * N_CLASSES + tid];
        logits[tid] = l;
    }
    __syncthreads();
    if (tid < N_CLASSES) {
        float m = -1e30f;
#pragma unroll
        for (int c = 0; c < N_CLASSES; c++) m = fmaxf(m, logits[c]);
        float s = 0.f;
#pragma unroll
        for (int c = 0; c < N_CLASSES; c++) s += expf(logits[c] - m);
        out[g * N_CLASSES + tid] = expf(logits[tid] - m) / s;
    }
}

extern "C" void kernel_launch(void* const* d_in, const int* in_sizes, int n_in,
                              void* d_out, int out_size, void* d_ws, size_t ws_size,
                              hipStream_t stream) {
    const float* x     = (const float*)d_in[0];
    const int*   ei    = (const int*)d_in[1];
    const int*   batch = (const int*)d_in[2];
    const float* W1 = (const float*)d_in[3];
    const float* b1 = (const float*)d_in[4];
    const float* W2 = (const float*)d_in[5];
    const float* b2 = (const float*)d_in[6];
    const float* W3 = (const float*)d_in[7];
    const float* b3 = (const float*)d_in[8];
    const float* Wl = (const float*)d_in[9];
    const float* bl = (const float*)d_in[10];
    float* out = (float*)d_out;

    const int* src = ei;            // edge_index[0]
    const int* dst = ei + N_EDGES;  // edge_index[1]

    // workspace layout
    int*   wsi     = (int*)d_ws;
    int*   counts  = wsi;                        // N_NODES
    int*   row_ptr = counts + N_NODES;           // N_NODES + 1
    int*   cursor  = row_ptr + N_NODES + 1;      // N_NODES
    int*   bsums   = cursor + N_NODES;           // 512
    int*   csr     = bsums + 512;                // N_EDGES
    float* dis     = (float*)(csr + N_EDGES);    // N_NODES
    float* g       = dis + N_NODES;              // N_NODES * 32
    float* h_agg   = g + N_NODES * H_DIM;        // N_NODES * 32

    // ---- CSR build (also yields degree -> dis) ----
    zero_counts_kernel<<<NBLK, 256, 0, stream>>>(counts);
    hist_sliced_kernel<<<NS * GPS, 256, 0, stream>>>(dst, counts);
    scan_part1_kernel<<<NBLK, 256, 0, stream>>>(counts, bsums);
    scan_part2_kernel<<<1, 512, 0, stream>>>(bsums);
    scan_part3_kernel<<<NBLK, 256, 0, stream>>>(counts, bsums, row_ptr, cursor, dis);
    fill_sliced_kernel<<<NS * GPS, 256, 0, stream>>>(src, dst, cursor, csr);

    // ---- layer 1 ----
    gemm128_kernel<<<N_NODES / 8, 256, 0, stream>>>(x, W1, dis, g);
    gather_kernel<<<N_NODES / 8, 256, 0, stream>>>(row_ptr, csr, g, dis, b1, h_agg);

    // ---- layer 2 ----
    gemm32_kernel<true><<<N_NODES / 32, 256, 0, stream>>>(h_agg, W2, dis, g);
    gather_kernel<<<N_NODES / 8, 256, 0, stream>>>(row_ptr, csr, g, dis, b2, h_agg);

    // ---- layer 3 ----
    gemm32_kernel<true><<<N_NODES / 32, 256, 0, stream>>>(h_agg, W3, dis, g);
    gather_kernel<<<N_NODES / 8, 256, 0, stream>>>(row_ptr, csr, g, dis, b3, h_agg);

    // ---- pool + classifier + softmax ----
    pool_head_kernel<<<N_GRAPHS, 256, 0, stream>>>(h_agg, batch, Wl, bl, out);
}